// Round 1
// baseline (319.025 us; speedup 1.0000x reference)
//
#include <hip/hip_runtime.h>
#include <cstddef>
#include <cstdint>

// Problem dims
constexpr int Nn = 4096;
constexpr int Ss = 128;
constexpr int Ff = 128;
constexpr int Dd = 256;
constexpr float EPSV = 1e-8f;

// d_out layout (floats): h_o [N*D], C_new [N*S*F], k [N*F], r [N*F]
constexpr size_t HO_OFF = 0;
constexpr size_t C_OFF  = (size_t)Nn * Dd;                 // 1,048,576
constexpr size_t K_OFF  = C_OFF + (size_t)Nn * Ss * Ff;    // 68,157,440
constexpr size_t R_OFF  = K_OFF + (size_t)Nn * Ff;         // 68,681,728

__device__ __forceinline__ float sigmf(float x) { return 1.0f / (1.0f + __expf(-x)); }

// ---------------------------------------------------------------------------
// Generic NT GEMM: out[n,j] = act( sum_k A[n,k]*Wrow(j)[k] + bias(j) )
// W: J x K row-major (weight rows contiguous). Optional second weight W2 for
// column range [split, J) (used to fuse e/v). ACT: 0 none, 2 sigmoid for j<split.
// Requires: N % BN == 0, J % BJ == 0, K % BK == 0, BN == BJ, (BN/TM)*(BJ/TN)==256.
// ---------------------------------------------------------------------------
template <int BN, int BJ, int BK, int TM, int TN, int ACT>
__global__ __launch_bounds__(256) void gemm_nt(
    const float* __restrict__ A, int K,
    const float* __restrict__ W, const float* __restrict__ W2, int split,
    const float* __restrict__ bias, const float* __restrict__ bias2,
    float* __restrict__ out, int J)
{
    constexpr int TX = BJ / TN;   // threads along J
    __shared__ float sA[BN][BK + 1];
    __shared__ float sW[BJ][BK + 1];

    const int t  = threadIdx.x;
    const int tx = t % TX;
    const int ty = t / TX;
    const int bn = blockIdx.x * BN;
    const int bj = blockIdx.y * BJ;

    float acc[TM][TN];
#pragma unroll
    for (int i = 0; i < TM; ++i)
#pragma unroll
        for (int j = 0; j < TN; ++j) acc[i][j] = 0.0f;

    const int nk = K / BK;
    for (int kc = 0; kc < nk; ++kc) {
#pragma unroll
        for (int u = 0; u < (BN * BK) / (4 * 256); ++u) {
            int idx = t + u * 256;
            int row = idx / (BK / 4);
            int c4  = idx % (BK / 4);
            float4 av = *(const float4*)(A + (size_t)(bn + row) * K + kc * BK + c4 * 4);
            sA[row][c4 * 4 + 0] = av.x;
            sA[row][c4 * 4 + 1] = av.y;
            sA[row][c4 * 4 + 2] = av.z;
            sA[row][c4 * 4 + 3] = av.w;
            int cg = bj + row;
            const float* wr = (split && cg >= split) ? (W2 + (size_t)(cg - split) * K)
                                                     : (W + (size_t)cg * K);
            float4 wv = *(const float4*)(wr + kc * BK + c4 * 4);
            sW[row][c4 * 4 + 0] = wv.x;
            sW[row][c4 * 4 + 1] = wv.y;
            sW[row][c4 * 4 + 2] = wv.z;
            sW[row][c4 * 4 + 3] = wv.w;
        }
        __syncthreads();
#pragma unroll
        for (int kk = 0; kk < BK; ++kk) {
            float a[TM], b[TN];
#pragma unroll
            for (int i = 0; i < TM; ++i) a[i] = sA[ty * TM + i][kk];
#pragma unroll
            for (int j = 0; j < TN; ++j) b[j] = sW[tx * TN + j][kk];
#pragma unroll
            for (int i = 0; i < TM; ++i)
#pragma unroll
                for (int j = 0; j < TN; ++j) acc[i][j] += a[i] * b[j];
        }
        __syncthreads();
    }

    // epilogue: TN contiguous columns per thread -> float4 stores
#pragma unroll
    for (int i = 0; i < TM; ++i) {
        int row = bn + ty * TM + i;
        float vals[TN];
#pragma unroll
        for (int j = 0; j < TN; ++j) {
            int cg  = bj + tx * TN + j;
            float b = (split && cg >= split) ? bias2[cg - split] : bias[cg];
            float x = acc[i][j] + b;
            if (ACT == 2 && cg < split) x = sigmf(x);
            vals[j] = x;
        }
#pragma unroll
        for (int j = 0; j < TN; j += 4) {
            float4 o = make_float4(vals[j], vals[j + 1], vals[j + 2], vals[j + 3]);
            *(float4*)(out + (size_t)row * J + bj + tx * TN + j) = o;
        }
    }
}

// ---------------------------------------------------------------------------
// beta[n] = softplus(h[n] . Wb + bb) + 1   (one wave per n)
// ---------------------------------------------------------------------------
__global__ __launch_bounds__(256) void beta_kernel(
    const float* __restrict__ h, const float* __restrict__ Wb,
    const float* __restrict__ bb, float* __restrict__ beta_out)
{
    int wid  = threadIdx.x >> 6;
    int lane = threadIdx.x & 63;
    int n    = blockIdx.x * 4 + wid;
    float4 hv = *(const float4*)(h + (size_t)n * Dd + lane * 4);
    float4 wv = *(const float4*)(Wb + lane * 4);
    float p = hv.x * wv.x + hv.y * wv.y + hv.z * wv.z + hv.w * wv.w;
#pragma unroll
    for (int o = 32; o > 0; o >>= 1) p += __shfl_xor(p, o);
    if (lane == 0) {
        float bp = p + bb[0];
        float sp = (bp > 20.0f) ? bp : log1pf(__expf(bp));
        beta_out[n] = sp + 1.0f;
    }
}

// ---------------------------------------------------------------------------
// Attention: per block n. Computes cosine scores, softmax w, r = w^T C.
// ---------------------------------------------------------------------------
__global__ __launch_bounds__(256) void attn_kernel(
    const float* __restrict__ C, const float* __restrict__ kvec,
    const float* __restrict__ beta_arr,
    float* __restrict__ w_out, float* __restrict__ r_out)
{
    const int n    = blockIdx.x;
    const int t    = threadIdx.x;
    const int lane = t & 63;
    const int wid  = t >> 6;
    const float* Cn = C + (size_t)n * Ss * Ff;

    __shared__ float sk[Ff];
    __shared__ float ssc[Ss];
    __shared__ float sred[8];
    __shared__ float sw[Ss];
    __shared__ float sr4[8][Ff];   // per-s-group partial r

    if (t < Ff) sk[t] = kvec[(size_t)n * Ff + t];
    __syncthreads();

    // k_norm
    float ks = 0.0f;
    if (t < Ff) { float kv = sk[t]; ks = kv * kv; }
#pragma unroll
    for (int o = 32; o > 0; o >>= 1) ks += __shfl_xor(ks, o);
    if (lane == 0) sred[wid] = ks;
    __syncthreads();
    const float knorm = fmaxf(sqrtf(sred[0] + sred[1]), EPSV);
    const float beta  = beta_arr[n];

    // pass 1: scores. wave wid handles rows [wid*32, wid*32+32), 2 rows/iter
#pragma unroll 4
    for (int it = 0; it < 16; ++it) {
        int s = wid * 32 + it * 2 + (lane >> 5);
        int f = (lane & 31) * 4;
        float4 c4 = *(const float4*)(Cn + (size_t)s * Ff + f);
        float d = c4.x * sk[f] + c4.y * sk[f + 1] + c4.z * sk[f + 2] + c4.w * sk[f + 3];
        float q = c4.x * c4.x + c4.y * c4.y + c4.z * c4.z + c4.w * c4.w;
#pragma unroll
        for (int o = 16; o > 0; o >>= 1) {
            d += __shfl_xor(d, o);
            q += __shfl_xor(q, o);
        }
        if ((lane & 31) == 0) {
            float cn = fmaxf(sqrtf(q), EPSV);
            ssc[s] = d / (cn * knorm);
        }
    }
    __syncthreads();

    // softmax over 128 scores (threads 0..127 own one each)
    float x = -INFINITY;
    if (t < Ss) x = ssc[t] * beta;
    float m = x;
#pragma unroll
    for (int o = 32; o > 0; o >>= 1) m = fmaxf(m, __shfl_xor(m, o));
    if (lane == 0) sred[wid] = m;
    __syncthreads();
    const float gm = fmaxf(sred[0], sred[1]);
    float ex = (t < Ss) ? __expf(x - gm) : 0.0f;
    float sm = ex;
#pragma unroll
    for (int o = 32; o > 0; o >>= 1) sm += __shfl_xor(sm, o);
    if (lane == 0) sred[4 + wid] = sm;
    __syncthreads();
    const float tot = sred[4] + sred[5];
    if (t < Ss) {
        float wv = ex / tot;
        sw[t] = wv;
        w_out[(size_t)n * Ss + t] = wv;
    }
    __syncthreads();

    // pass 2: r[f] = sum_s w[s]*C[s][f]. thread: f4 = (t&31)*4, s-group = t>>5
    const int f4 = (t & 31) * 4;
    const int sg = t >> 5;
    float4 racc = make_float4(0.f, 0.f, 0.f, 0.f);
#pragma unroll 4
    for (int j = 0; j < 16; ++j) {
        int s = sg * 16 + j;
        float wv = sw[s];
        float4 c4 = *(const float4*)(Cn + (size_t)s * Ff + f4);
        racc.x += wv * c4.x;
        racc.y += wv * c4.y;
        racc.z += wv * c4.z;
        racc.w += wv * c4.w;
    }
    *(float4*)(&sr4[sg][f4]) = racc;
    __syncthreads();
    if (t < 32) {
        float4 rr = *(float4*)(&sr4[0][t * 4]);
#pragma unroll
        for (int g = 1; g < 8; ++g) {
            float4 p = *(float4*)(&sr4[g][t * 4]);
            rr.x += p.x; rr.y += p.y; rr.z += p.z; rr.w += p.w;
        }
        *(float4*)(r_out + (size_t)n * Ff + t * 4) = rr;
    }
}

// ---------------------------------------------------------------------------
// Gates: h_o = (1-z)*tanh(i_n + rg*h_n) + z*h_prev
// ---------------------------------------------------------------------------
__global__ __launch_bounds__(256) void gates_kernel(
    const float* __restrict__ gi, const float* __restrict__ gh,
    const float* __restrict__ hprev, float* __restrict__ ho)
{
    int idx = blockIdx.x * blockDim.x + threadIdx.x;  // over N*D/4
    int n  = idx >> 6;
    int d4 = (idx & 63) * 4;
    const float* gin = gi + (size_t)n * 768;
    const float* ghn = gh + (size_t)n * 768;
    float4 ir = *(const float4*)(gin + d4);
    float4 iz = *(const float4*)(gin + 256 + d4);
    float4 in_ = *(const float4*)(gin + 512 + d4);
    float4 hr = *(const float4*)(ghn + d4);
    float4 hz = *(const float4*)(ghn + 256 + d4);
    float4 hn = *(const float4*)(ghn + 512 + d4);
    float4 hp = *(const float4*)(hprev + (size_t)n * Dd + d4);
    float4 o;
    {
        float rg = sigmf(ir.x + hr.x); float z = sigmf(iz.x + hz.x);
        float nn = tanhf(in_.x + rg * hn.x); o.x = (1.0f - z) * nn + z * hp.x;
    }
    {
        float rg = sigmf(ir.y + hr.y); float z = sigmf(iz.y + hz.y);
        float nn = tanhf(in_.y + rg * hn.y); o.y = (1.0f - z) * nn + z * hp.y;
    }
    {
        float rg = sigmf(ir.z + hr.z); float z = sigmf(iz.z + hz.z);
        float nn = tanhf(in_.z + rg * hn.z); o.z = (1.0f - z) * nn + z * hp.z;
    }
    {
        float rg = sigmf(ir.w + hr.w); float z = sigmf(iz.w + hz.w);
        float nn = tanhf(in_.w + rg * hn.w); o.w = (1.0f - z) * nn + z * hp.w;
    }
    *(float4*)(ho + (size_t)n * Dd + d4) = o;
}

// ---------------------------------------------------------------------------
// C_new = C*(1 - w*e) + w*v    (ev: N x 256, e = [:,:128], v = [:,128:])
// ---------------------------------------------------------------------------
__global__ __launch_bounds__(256) void update_kernel(
    const float* __restrict__ C, const float* __restrict__ w,
    const float* __restrict__ ev, float* __restrict__ Cnew)
{
    const size_t total4 = (size_t)Nn * Ss * Ff / 4;
    const size_t stride = (size_t)gridDim.x * blockDim.x;
    for (size_t i = (size_t)blockIdx.x * blockDim.x + threadIdx.x; i < total4; i += stride) {
        int n   = (int)(i >> 12);
        int rem = (int)(i & 4095);
        int s   = rem >> 5;
        int f4  = (rem & 31) * 4;
        float wv = w[(size_t)n * Ss + s];
        float4 e4 = *(const float4*)(ev + (size_t)n * 256 + f4);
        float4 v4 = *(const float4*)(ev + (size_t)n * 256 + 128 + f4);
        float4 c4 = *(const float4*)(C + i * 4);
        float4 o;
        o.x = c4.x * (1.0f - wv * e4.x) + wv * v4.x;
        o.y = c4.y * (1.0f - wv * e4.y) + wv * v4.y;
        o.z = c4.z * (1.0f - wv * e4.z) + wv * v4.z;
        o.w = c4.w * (1.0f - wv * e4.w) + wv * v4.w;
        *(float4*)(Cnew + i * 4) = o;
    }
}

// ---------------------------------------------------------------------------
extern "C" void kernel_launch(void* const* d_in, const int* in_sizes, int n_in,
                              void* d_out, int out_size, void* d_ws, size_t ws_size,
                              hipStream_t stream)
{
    const float* h_prev = (const float*)d_in[0];
    const float* C      = (const float*)d_in[1];
    const float* Wk     = (const float*)d_in[2];
    const float* bk     = (const float*)d_in[3];
    const float* Wb     = (const float*)d_in[4];
    const float* bb     = (const float*)d_in[5];
    const float* We     = (const float*)d_in[6];
    const float* be     = (const float*)d_in[7];
    const float* Wv     = (const float*)d_in[8];
    const float* bv     = (const float*)d_in[9];
    const float* Wih    = (const float*)d_in[10];
    const float* Whh    = (const float*)d_in[11];
    const float* bih    = (const float*)d_in[12];
    const float* bhh    = (const float*)d_in[13];

    float* out  = (float*)d_out;
    float* ho   = out + HO_OFF;
    float* Cnew = out + C_OFF;
    float* kbuf = out + K_OFF;
    float* rbuf = out + R_OFF;

    // ws layout (floats)
    float* ws      = (float*)d_ws;
    float* ws_gh   = ws;                         // N*768
    float* ws_gi   = ws_gh + (size_t)Nn * 768;   // N*768
    float* ws_beta = ws_gi + (size_t)Nn * 768;   // N
    float* ws_w    = ws_beta + Nn;               // N*128
    float* ws_ev   = ws_w + (size_t)Nn * Ss;     // N*256

    // G1: gh = h_prev @ Whh.T + bhh   (4096 x 768, K=256)
    gemm_nt<128, 128, 16, 8, 8, 0><<<dim3(Nn / 128, 768 / 128), 256, 0, stream>>>(
        h_prev, Dd, Whh, nullptr, 0, bhh, nullptr, ws_gh, 768);

    // G2: k = h_prev @ Wk.T + bk      (4096 x 128, K=256)
    gemm_nt<64, 64, 32, 4, 4, 0><<<dim3(Nn / 64, 128 / 64), 256, 0, stream>>>(
        h_prev, Dd, Wk, nullptr, 0, bk, nullptr, kbuf, 128);

    // beta
    beta_kernel<<<Nn / 4, 256, 0, stream>>>(h_prev, Wb, bb, ws_beta);

    // attention: w, r
    attn_kernel<<<Nn, 256, 0, stream>>>(C, kbuf, ws_beta, ws_w, rbuf);

    // G3: gi = r @ Wih.T + bih        (4096 x 768, K=128)
    gemm_nt<128, 128, 16, 8, 8, 0><<<dim3(Nn / 128, 768 / 128), 256, 0, stream>>>(
        rbuf, Ff, Wih, nullptr, 0, bih, nullptr, ws_gi, 768);

    // gates -> h_o
    gates_kernel<<<(Nn * Dd / 4) / 256, 256, 0, stream>>>(ws_gi, ws_gh, h_prev, ho);

    // G4: [e|v] = h_o @ [We;Wv].T (sigmoid on e)   (4096 x 256, K=256)
    gemm_nt<64, 64, 32, 4, 4, 2><<<dim3(Nn / 64, 256 / 64), 256, 0, stream>>>(
        ho, Dd, We, Wv, 128, be, bv, ws_ev, 256);

    // update -> C_new
    update_kernel<<<8192, 256, 0, stream>>>(C, ws_w, ws_ev, Cnew);
}

// Round 3
// 227.839 us; speedup vs baseline: 1.4002x; 1.4002x over previous
//
#include <hip/hip_runtime.h>
#include <hip/hip_bf16.h>
#include <cstddef>
#include <cstdint>

// Problem dims
constexpr int Nn = 4096;
constexpr int Ss = 128;
constexpr int Ff = 128;
constexpr int Dd = 256;
constexpr float EPSV = 1e-8f;

// d_out layout (floats): h_o [N*D], C_new [N*S*F], k [N*F], r [N*F]
constexpr size_t HO_OFF = 0;
constexpr size_t C_OFF  = (size_t)Nn * Dd;
constexpr size_t K_OFF  = C_OFF + (size_t)Nn * Ss * Ff;
constexpr size_t R_OFF  = K_OFF + (size_t)Nn * Ff;

typedef __attribute__((ext_vector_type(4))) float f4v;   // MFMA C/D frag / NT access
typedef __attribute__((ext_vector_type(8))) short bh8;   // MFMA A/B frag (8 bf16)

__device__ __forceinline__ float sigmf(float x) { return 1.0f / (1.0f + __expf(-x)); }

__device__ __forceinline__ short f2bf(float x) {
    __hip_bfloat16 h = __float2bfloat16(x);   // RNE
    return *reinterpret_cast<short*>(&h);
}

// ---------------------------------------------------------------------------
// bf16 MFMA GEMM:  out[n, j] = act( sum_k A[n,k] * Wrow(j)[k] + bias(j) )
// A: fp32 N x K row-major. Weight rows: col<splitW from W1, else W2 (row col-splitW).
// Output: col<splitOut -> out1[row*J1+col], else out2[row*J2+(col-splitOut)].
// SIGSPLIT!=0: sigmoid applied for col < SIGSPLIT.
// Tile 64x64, BK=32, 4 waves (2x2), each wave 32x32 via 2x2 16x16x32 MFMA frags.
// LDS tiles swizzled: 16B k-group slot XORed with (row&3) -> 4-way max conflict.
// ---------------------------------------------------------------------------
template <int SIGSPLIT>
__global__ __launch_bounds__(256) void mfma_gemm(
    const float* __restrict__ A, int K,
    const float* __restrict__ W1, const float* __restrict__ W2, int splitW,
    const float* __restrict__ b1, const float* __restrict__ b2,
    float* __restrict__ out1, int J1,
    float* __restrict__ out2, int J2, int splitOut)
{
    __shared__ __align__(16) short sA[64 * 32];
    __shared__ __align__(16) short sW[64 * 32];

    const int t  = threadIdx.x;
    const int bm = blockIdx.x * 64;
    const int bj = blockIdx.y * 64;

    // staging role: thread t owns row/col r, k-group kg (8 k-values)
    const int r  = t >> 2;
    const int kg = t & 3;
    const float* aRow = A + (size_t)(bm + r) * K;
    const int   colS  = bj + r;
    const float* wRow = (colS < splitW) ? (W1 + (size_t)colS * K)
                                        : (W2 + (size_t)(colS - splitW) * K);
    const int swzSt = r * 32 + ((kg ^ (r & 3)) << 3);

    // compute role
    const int l   = t & 63;
    const int wv  = t >> 6;
    const int wr  = wv >> 1;
    const int wc  = wv & 1;
    const int kgr = l >> 4;          // which 8-k group this lane reads
    const int fr  = l & 15;          // fragment row/col index

    f4v acc[2][2];
#pragma unroll
    for (int m = 0; m < 2; ++m)
#pragma unroll
        for (int n2 = 0; n2 < 2; ++n2) acc[m][n2] = f4v{0.f, 0.f, 0.f, 0.f};

    const int nk = K / 32;
    for (int kc = 0; kc < nk; ++kc) {
        const int k0 = kc * 32 + kg * 8;
        float4 a0 = *(const float4*)(aRow + k0);
        float4 a1 = *(const float4*)(aRow + k0 + 4);
        float4 w0 = *(const float4*)(wRow + k0);
        float4 w1 = *(const float4*)(wRow + k0 + 4);
        bh8 av = { f2bf(a0.x), f2bf(a0.y), f2bf(a0.z), f2bf(a0.w),
                   f2bf(a1.x), f2bf(a1.y), f2bf(a1.z), f2bf(a1.w) };
        bh8 wvv= { f2bf(w0.x), f2bf(w0.y), f2bf(w0.z), f2bf(w0.w),
                   f2bf(w1.x), f2bf(w1.y), f2bf(w1.z), f2bf(w1.w) };
        __syncthreads();                 // previous chunk fully consumed
        *(bh8*)(sA + swzSt) = av;
        *(bh8*)(sW + swzSt) = wvv;
        __syncthreads();                 // tiles ready

        bh8 af[2], bf[2];
#pragma unroll
        for (int m = 0; m < 2; ++m) {
            int ar = wr * 32 + m * 16 + fr;
            af[m] = *(bh8*)(sA + ar * 32 + ((kgr ^ (ar & 3)) << 3));
            int bc = wc * 32 + m * 16 + fr;
            bf[m] = *(bh8*)(sW + bc * 32 + ((kgr ^ (bc & 3)) << 3));
        }
#pragma unroll
        for (int m = 0; m < 2; ++m)
#pragma unroll
            for (int n2 = 0; n2 < 2; ++n2)
                acc[m][n2] = __builtin_amdgcn_mfma_f32_16x16x32_bf16(
                    af[m], bf[n2], acc[m][n2], 0, 0, 0);
    }

    // epilogue: C/D frag layout col = l&15, row = (l>>4)*4 + reg
#pragma unroll
    for (int n2 = 0; n2 < 2; ++n2) {
        const int colg = bj + wc * 32 + n2 * 16 + fr;
        const float bs = (colg < splitW) ? b1[colg] : b2[colg - splitW];
        float* base; int jj;
        if (colg < splitOut) { base = out1 + colg;              jj = J1; }
        else                 { base = out2 + (colg - splitOut); jj = J2; }
#pragma unroll
        for (int m = 0; m < 2; ++m) {
#pragma unroll
            for (int rg = 0; rg < 4; ++rg) {
                float x = acc[m][n2][rg] + bs;
                if (SIGSPLIT && colg < SIGSPLIT) x = sigmf(x);
                const int rowg = bm + wr * 32 + m * 16 + kgr * 4 + rg;
                base[(size_t)rowg * jj] = x;
            }
        }
    }
}

// ---------------------------------------------------------------------------
// beta[n] = softplus(h[n] . Wb + bb) + 1   (one wave per n)
// ---------------------------------------------------------------------------
__global__ __launch_bounds__(256) void beta_kernel(
    const float* __restrict__ h, const float* __restrict__ Wb,
    const float* __restrict__ bb, float* __restrict__ beta_out)
{
    int wid  = threadIdx.x >> 6;
    int lane = threadIdx.x & 63;
    int n    = blockIdx.x * 4 + wid;
    float4 hv = *(const float4*)(h + (size_t)n * Dd + lane * 4);
    float4 wv = *(const float4*)(Wb + lane * 4);
    float p = hv.x * wv.x + hv.y * wv.y + hv.z * wv.z + hv.w * wv.w;
#pragma unroll
    for (int o = 32; o > 0; o >>= 1) p += __shfl_xor(p, o);
    if (lane == 0) {
        float bp = p + bb[0];
        float sp = (bp > 20.0f) ? bp : log1pf(__expf(bp));
        beta_out[n] = sp + 1.0f;
    }
}

// ---------------------------------------------------------------------------
// Attention: per block n. Cosine scores, softmax w, r = w^T C.
// ---------------------------------------------------------------------------
__global__ __launch_bounds__(256) void attn_kernel(
    const float* __restrict__ C, const float* __restrict__ kvec,
    const float* __restrict__ beta_arr,
    float* __restrict__ w_out, float* __restrict__ r_out)
{
    const int n    = blockIdx.x;
    const int t    = threadIdx.x;
    const int lane = t & 63;
    const int wid  = t >> 6;
    const float* Cn = C + (size_t)n * Ss * Ff;

    __shared__ float sk[Ff];
    __shared__ float ssc[Ss];
    __shared__ float sred[8];
    __shared__ float sw[Ss];
    __shared__ float sr4[8][Ff];

    if (t < Ff) sk[t] = kvec[(size_t)n * Ff + t];
    __syncthreads();

    float ks = 0.0f;
    if (t < Ff) { float kv = sk[t]; ks = kv * kv; }
#pragma unroll
    for (int o = 32; o > 0; o >>= 1) ks += __shfl_xor(ks, o);
    if (lane == 0) sred[wid] = ks;
    __syncthreads();
    const float knorm = fmaxf(sqrtf(sred[0] + sred[1]), EPSV);
    const float beta  = beta_arr[n];

#pragma unroll 4
    for (int it = 0; it < 16; ++it) {
        int s = wid * 32 + it * 2 + (lane >> 5);
        int f = (lane & 31) * 4;
        float4 c4 = *(const float4*)(Cn + (size_t)s * Ff + f);
        float d = c4.x * sk[f] + c4.y * sk[f + 1] + c4.z * sk[f + 2] + c4.w * sk[f + 3];
        float q = c4.x * c4.x + c4.y * c4.y + c4.z * c4.z + c4.w * c4.w;
#pragma unroll
        for (int o = 16; o > 0; o >>= 1) {
            d += __shfl_xor(d, o);
            q += __shfl_xor(q, o);
        }
        if ((lane & 31) == 0) {
            float cn = fmaxf(sqrtf(q), EPSV);
            ssc[s] = d / (cn * knorm);
        }
    }
    __syncthreads();

    float x = -INFINITY;
    if (t < Ss) x = ssc[t] * beta;
    float m = x;
#pragma unroll
    for (int o = 32; o > 0; o >>= 1) m = fmaxf(m, __shfl_xor(m, o));
    if (lane == 0) sred[wid] = m;
    __syncthreads();
    const float gm = fmaxf(sred[0], sred[1]);
    float ex = (t < Ss) ? __expf(x - gm) : 0.0f;
    float sm = ex;
#pragma unroll
    for (int o = 32; o > 0; o >>= 1) sm += __shfl_xor(sm, o);
    if (lane == 0) sred[4 + wid] = sm;
    __syncthreads();
    const float tot = sred[4] + sred[5];
    if (t < Ss) {
        float wvl = ex / tot;
        sw[t] = wvl;
        w_out[(size_t)n * Ss + t] = wvl;
    }
    __syncthreads();

    const int f4 = (t & 31) * 4;
    const int sg = t >> 5;
    float4 racc = make_float4(0.f, 0.f, 0.f, 0.f);
#pragma unroll 4
    for (int j = 0; j < 16; ++j) {
        int s = sg * 16 + j;
        float wvl = sw[s];
        float4 c4 = *(const float4*)(Cn + (size_t)s * Ff + f4);
        racc.x += wvl * c4.x;
        racc.y += wvl * c4.y;
        racc.z += wvl * c4.z;
        racc.w += wvl * c4.w;
    }
    *(float4*)(&sr4[sg][f4]) = racc;
    __syncthreads();
    if (t < 32) {
        float4 rr = *(float4*)(&sr4[0][t * 4]);
#pragma unroll
        for (int g = 1; g < 8; ++g) {
            float4 p = *(float4*)(&sr4[g][t * 4]);
            rr.x += p.x; rr.y += p.y; rr.z += p.z; rr.w += p.w;
        }
        *(float4*)(r_out + (size_t)n * Ff + t * 4) = rr;
    }
}

// ---------------------------------------------------------------------------
// Gates: h_o = (1-z)*tanh(i_n + rg*h_n) + z*h_prev
// ---------------------------------------------------------------------------
__global__ __launch_bounds__(256) void gates_kernel(
    const float* __restrict__ gi, const float* __restrict__ gh,
    const float* __restrict__ hprev, float* __restrict__ ho)
{
    int idx = blockIdx.x * blockDim.x + threadIdx.x;
    int n  = idx >> 6;
    int d4 = (idx & 63) * 4;
    const float* gin = gi + (size_t)n * 768;
    const float* ghn = gh + (size_t)n * 768;
    float4 ir = *(const float4*)(gin + d4);
    float4 iz = *(const float4*)(gin + 256 + d4);
    float4 in_ = *(const float4*)(gin + 512 + d4);
    float4 hr = *(const float4*)(ghn + d4);
    float4 hz = *(const float4*)(ghn + 256 + d4);
    float4 hn = *(const float4*)(ghn + 512 + d4);
    float4 hp = *(const float4*)(hprev + (size_t)n * Dd + d4);
    float4 o;
    { float rg = sigmf(ir.x + hr.x); float z = sigmf(iz.x + hz.x);
      float nn = tanhf(in_.x + rg * hn.x); o.x = (1.0f - z) * nn + z * hp.x; }
    { float rg = sigmf(ir.y + hr.y); float z = sigmf(iz.y + hz.y);
      float nn = tanhf(in_.y + rg * hn.y); o.y = (1.0f - z) * nn + z * hp.y; }
    { float rg = sigmf(ir.z + hr.z); float z = sigmf(iz.z + hz.z);
      float nn = tanhf(in_.z + rg * hn.z); o.z = (1.0f - z) * nn + z * hp.z; }
    { float rg = sigmf(ir.w + hr.w); float z = sigmf(iz.w + hz.w);
      float nn = tanhf(in_.w + rg * hn.w); o.w = (1.0f - z) * nn + z * hp.w; }
    *(float4*)(ho + (size_t)n * Dd + d4) = o;
}

// ---------------------------------------------------------------------------
// C_new = C*(1 - w*e) + w*v. Descending chunk order + nontemporal C/C_new so
// the tail of C (still L3-resident from attn) is hit and not evicted by the
// C_new write stream.
// ---------------------------------------------------------------------------
__global__ __launch_bounds__(256) void update_kernel(
    const float* __restrict__ C, const float* __restrict__ w,
    const float* __restrict__ ev, float* __restrict__ Cnew)
{
    const size_t total4 = (size_t)Nn * Ss * Ff / 4;
    const size_t stride = (size_t)gridDim.x * blockDim.x;
    const size_t lin    = (size_t)blockIdx.x * blockDim.x + threadIdx.x;
    const int nIter     = (int)(total4 / stride);
    for (int it = nIter - 1; it >= 0; --it) {
        size_t i = (size_t)it * stride + lin;
        int n   = (int)(i >> 12);
        int rem = (int)(i & 4095);
        int s   = rem >> 5;
        int f4  = (rem & 31) * 4;
        float wv = w[(size_t)n * Ss + s];
        float4 e4 = *(const float4*)(ev + (size_t)n * 256 + f4);
        float4 v4 = *(const float4*)(ev + (size_t)n * 256 + 128 + f4);
        f4v c4 = __builtin_nontemporal_load((const f4v*)(C + i * 4));
        f4v o;
        o.x = c4.x * (1.0f - wv * e4.x) + wv * v4.x;
        o.y = c4.y * (1.0f - wv * e4.y) + wv * v4.y;
        o.z = c4.z * (1.0f - wv * e4.z) + wv * v4.z;
        o.w = c4.w * (1.0f - wv * e4.w) + wv * v4.w;
        __builtin_nontemporal_store(o, (f4v*)(Cnew + i * 4));
    }
}

// ---------------------------------------------------------------------------
extern "C" void kernel_launch(void* const* d_in, const int* in_sizes, int n_in,
                              void* d_out, int out_size, void* d_ws, size_t ws_size,
                              hipStream_t stream)
{
    const float* h_prev = (const float*)d_in[0];
    const float* C      = (const float*)d_in[1];
    const float* Wk     = (const float*)d_in[2];
    const float* bk     = (const float*)d_in[3];
    const float* Wb     = (const float*)d_in[4];
    const float* bb     = (const float*)d_in[5];
    const float* We     = (const float*)d_in[6];
    const float* be     = (const float*)d_in[7];
    const float* Wv     = (const float*)d_in[8];
    const float* bv     = (const float*)d_in[9];
    const float* Wih    = (const float*)d_in[10];
    const float* Whh    = (const float*)d_in[11];
    const float* bih    = (const float*)d_in[12];
    const float* bhh    = (const float*)d_in[13];

    float* out  = (float*)d_out;
    float* ho   = out + HO_OFF;
    float* Cnew = out + C_OFF;
    float* kbuf = out + K_OFF;
    float* rbuf = out + R_OFF;

    float* ws      = (float*)d_ws;
    float* ws_gh   = ws;                         // N*768
    float* ws_gi   = ws_gh + (size_t)Nn * 768;   // N*768
    float* ws_beta = ws_gi + (size_t)Nn * 768;   // N
    float* ws_w    = ws_beta + Nn;               // N*128
    float* ws_ev   = ws_w + (size_t)Nn * Ss;     // N*256

    // GEMM_A: [gh | k] = h_prev @ [Whh;Wk].T   (4096 x 896, K=256)
    mfma_gemm<0><<<dim3(Nn / 64, 896 / 64), 256, 0, stream>>>(
        h_prev, Dd, Whh, Wk, 768, bhh, bk, ws_gh, 768, kbuf, 128, 768);

    // beta
    beta_kernel<<<Nn / 4, 256, 0, stream>>>(h_prev, Wb, bb, ws_beta);

    // attention: w, r
    attn_kernel<<<Nn, 256, 0, stream>>>(C, kbuf, ws_beta, ws_w, rbuf);

    // GEMM_B: gi = r @ Wih.T   (4096 x 768, K=128)
    mfma_gemm<0><<<dim3(Nn / 64, 768 / 64), 256, 0, stream>>>(
        rbuf, Ff, Wih, Wih, 768, bih, bih, ws_gi, 768, nullptr, 0, 768);

    // gates -> h_o
    gates_kernel<<<(Nn * Dd / 4) / 256, 256, 0, stream>>>(ws_gi, ws_gh, h_prev, ho);

    // GEMM_C: [e|v] = h_o @ [We;Wv].T, sigmoid on e   (4096 x 256, K=256)
    mfma_gemm<128><<<dim3(Nn / 64, 256 / 64), 256, 0, stream>>>(
        ho, Dd, We, Wv, 128, be, bv, ws_ev, 256, nullptr, 0, 256);

    // update -> C_new
    update_kernel<<<8192, 256, 0, stream>>>(C, ws_w, ws_ev, Cnew);
}